// Round 1
// baseline (108765.125 us; speedup 1.0000x reference)
//
#include <hip/hip_runtime.h>
#include <math.h>

#define NWG 256
#define TPB 512
#define AGT __HIP_MEMORY_SCOPE_AGENT

// ---- sizes ----
static constexpr int Bb = 32, Dd = 512, Tt = 32, Vv = 32000;
static constexpr int BD = Bb * Dd;                       // 16384
static constexpr float SCALE_INV = 0.04419417382415922f; // 1/sqrt(512)

// ---- ws layout (float offsets) ----
static constexpr size_t OFF_H0 = 512;                    // sync region first 2KB
static constexpr size_t OFF_H1 = OFF_H0 + 2 * (size_t)BD;
static constexpr size_t OFF_P  = OFF_H1 + 2 * (size_t)BD;             // [32][32][2048]
static constexpr size_t OFF_HL = OFF_P + (size_t)Tt * Bb * 2048;      // [32][32][512]
static constexpr size_t OFF_OT = OFF_HL + (size_t)Tt * BD;
static constexpr size_t OFF_CX = OFF_OT + BD;
static constexpr size_t OFF_HD = OFF_CX + BD;
static constexpr size_t OFF_OF = OFF_HD + BD;                          // [32][32][512]
static constexpr size_t OFF_CV = OFF_OF + (size_t)Tt * BD;             // [32][256]
static constexpr size_t OFF_CI = OFF_CV + 32 * 256;
static constexpr size_t OFF_ET = OFF_CI + 32 * 256;                    // [512][32000]

__device__ __forceinline__ float sigm(float x) { return 1.0f / (1.0f + expf(-x)); }

__device__ __forceinline__ float wredsum(float v) {
#pragma unroll
  for (int off = 32; off > 0; off >>= 1) v += __shfl_xor(v, off, 64);
  return v;
}

// ---- 2-level grid barrier (256 WGs = 8 groups of 32) ----
__device__ __forceinline__ void gbar(unsigned* sb, unsigned& lg) {
  __threadfence();
  __syncthreads();
  if (threadIdx.x == 0) {
    const int g = (int)blockIdx.x >> 5;
    unsigned a = __hip_atomic_fetch_add(&sb[g * 32], 1u, __ATOMIC_ACQ_REL, AGT);
    bool rel = false;
    if (a == 31u) {
      __hip_atomic_store(&sb[g * 32], 0u, __ATOMIC_RELAXED, AGT);
      unsigned r = __hip_atomic_fetch_add(&sb[256], 1u, __ATOMIC_ACQ_REL, AGT);
      if (r == 7u) {
        __hip_atomic_store(&sb[256], 0u, __ATOMIC_RELAXED, AGT);
        __hip_atomic_store(&sb[288], lg + 1u, __ATOMIC_RELEASE, AGT);
        rel = true;
      }
    }
    if (!rel) {
      while (__hip_atomic_load(&sb[288], __ATOMIC_ACQUIRE, AGT) == lg)
        __builtin_amdgcn_s_sleep(1);
    }
  }
  lg += 1u;
  __syncthreads();
  __threadfence();
}

__device__ __forceinline__ float blockMax(float v, float* red, int tid) {
#pragma unroll
  for (int off = 32; off > 0; off >>= 1) v = fmaxf(v, __shfl_xor(v, off, 64));
  if ((tid & 63) == 0) red[tid >> 6] = v;
  __syncthreads();
  float m = red[0];
#pragma unroll
  for (int i = 1; i < 8; ++i) m = fmaxf(m, red[i]);
  __syncthreads();
  return m;
}

__device__ __forceinline__ float blockSum(float v, float* red, int tid) {
  v = wredsum(v);
  if ((tid & 63) == 0) red[tid >> 6] = v;
  __syncthreads();
  float s = 0.f;
#pragma unroll
  for (int i = 0; i < 8; ++i) s += red[i];
  __syncthreads();
  return s;
}

// ---- stage this WG's 24 weight rows into LDS (slant-packed: chunk kc at kc*36) ----
__device__ void stageW(int wg, int tid, const float* __restrict__ Wih,
                       const float* __restrict__ Whh, float* __restrict__ SM) {
  for (int e = tid; e < 3 * 8 * 512; e += TPB) {
    const int k = e & 511, jl = (e >> 9) & 7, m = e >> 12;
    const int q = jl >> 1, dl = jl & 1;
    const int j = q * 512 + wg * 2 + dl;
    const float* srcp = (m == 0) ? (Whh + (size_t)j * 512)
                     : (m == 1) ? (Wih + (size_t)2048 * 512 + (size_t)j * 512)
                                : (Whh + (size_t)2048 * 512 + (size_t)j * 512);
    SM[(m * 8 + jl) * 576 + (k >> 5) * 36 + (k & 31)] = srcp[k];
  }
  __syncthreads();
}

// ---- one-time transpose of trg_emb into ET[512][32000] ----
__device__ void transposeET(int wg, int tid, const float* __restrict__ Etrg,
                            float* __restrict__ ETw, float* __restrict__ SM) {
  for (int tile = wg; tile < 2000; tile += NWG) {
    const int tv = tile >> 2, tk = tile & 3;
    __syncthreads();
    for (int e = tid; e < 64 * 128; e += TPB) {
      const int vl = e >> 7, kl = e & 127;
      SM[vl * 129 + kl] = Etrg[(size_t)(tv * 64 + vl) * 512 + tk * 128 + kl];
    }
    __syncthreads();
    for (int e = tid; e < 64 * 128; e += TPB) {
      const int kl = e >> 6, vl = e & 63;
      ETw[(size_t)(tk * 128 + kl) * 32000 + tv * 64 + vl] = SM[vl * 129 + kl];
    }
  }
  __syncthreads();
}

// ---- merged LSTM phase: A = L0(pos p), B = L1(pos p-1). Both read H0r; B reads H1r. ----
__device__ __forceinline__ void phaseAB(
    int wg, int tid, bool doA, bool doB,
    const float* __restrict__ H0r, float* __restrict__ H0w,
    const float* __restrict__ H1r, float* __restrict__ H1w,
    float* __restrict__ HlP, const float* __restrict__ Pp,
    const float* __restrict__ bih, const float* __restrict__ bhh,
    float* __restrict__ SM, float& c0, float& c1)
{
  const int kc = tid & 15;          // k-chunk (32 k each)
  const int b4 = (tid >> 4) & 7;    // group of 4 batch rows
  const int jlp = tid >> 7;         // pair of weight rows
  float hreg[4][32];
#pragma unroll
  for (int bb = 0; bb < 4; ++bb) {
    const float4* s = (const float4*)(H0r + (b4 * 4 + bb) * 512 + kc * 32);
#pragma unroll
    for (int f = 0; f < 8; ++f) {
      float4 v = s[f];
      hreg[bb][f * 4 + 0] = v.x; hreg[bb][f * 4 + 1] = v.y;
      hreg[bb][f * 4 + 2] = v.z; hreg[bb][f * 4 + 3] = v.w;
    }
  }
  float accA[2][4] = {{0.f,0.f,0.f,0.f},{0.f,0.f,0.f,0.f}};
  float accB[2][4] = {{0.f,0.f,0.f,0.f},{0.f,0.f,0.f,0.f}};
  if (doA) {
#pragma unroll
    for (int j2 = 0; j2 < 2; ++j2) {
      const float* wr = SM + (jlp * 2 + j2) * 576 + kc * 36;
#pragma unroll
      for (int iq = 0; iq < 8; ++iq) {
        const float4 w = ((const float4*)wr)[iq];
#pragma unroll
        for (int bb = 0; bb < 4; ++bb) {
          accA[j2][bb] = fmaf(w.x, hreg[bb][iq*4+0], accA[j2][bb]);
          accA[j2][bb] = fmaf(w.y, hreg[bb][iq*4+1], accA[j2][bb]);
          accA[j2][bb] = fmaf(w.z, hreg[bb][iq*4+2], accA[j2][bb]);
          accA[j2][bb] = fmaf(w.w, hreg[bb][iq*4+3], accA[j2][bb]);
        }
      }
    }
  }
  if (doB) {
#pragma unroll
    for (int j2 = 0; j2 < 2; ++j2) {           // Wih1 · H0
      const float* wr = SM + (8 + jlp * 2 + j2) * 576 + kc * 36;
#pragma unroll
      for (int iq = 0; iq < 8; ++iq) {
        const float4 w = ((const float4*)wr)[iq];
#pragma unroll
        for (int bb = 0; bb < 4; ++bb) {
          accB[j2][bb] = fmaf(w.x, hreg[bb][iq*4+0], accB[j2][bb]);
          accB[j2][bb] = fmaf(w.y, hreg[bb][iq*4+1], accB[j2][bb]);
          accB[j2][bb] = fmaf(w.z, hreg[bb][iq*4+2], accB[j2][bb]);
          accB[j2][bb] = fmaf(w.w, hreg[bb][iq*4+3], accB[j2][bb]);
        }
      }
    }
#pragma unroll
    for (int bb = 0; bb < 4; ++bb) {           // reload H1 into hreg
      const float4* s = (const float4*)(H1r + (b4 * 4 + bb) * 512 + kc * 32);
#pragma unroll
      for (int f = 0; f < 8; ++f) {
        float4 v = s[f];
        hreg[bb][f * 4 + 0] = v.x; hreg[bb][f * 4 + 1] = v.y;
        hreg[bb][f * 4 + 2] = v.z; hreg[bb][f * 4 + 3] = v.w;
      }
    }
#pragma unroll
    for (int j2 = 0; j2 < 2; ++j2) {           // Whh1 · H1
      const float* wr = SM + (16 + jlp * 2 + j2) * 576 + kc * 36;
#pragma unroll
      for (int iq = 0; iq < 8; ++iq) {
        const float4 w = ((const float4*)wr)[iq];
#pragma unroll
        for (int bb = 0; bb < 4; ++bb) {
          accB[j2][bb] = fmaf(w.x, hreg[bb][iq*4+0], accB[j2][bb]);
          accB[j2][bb] = fmaf(w.y, hreg[bb][iq*4+1], accB[j2][bb]);
          accB[j2][bb] = fmaf(w.z, hreg[bb][iq*4+2], accB[j2][bb]);
          accB[j2][bb] = fmaf(w.w, hreg[bb][iq*4+3], accB[j2][bb]);
        }
      }
    }
  }
#pragma unroll
  for (int off = 1; off < 16; off <<= 1) {     // reduce over kc lanes
#pragma unroll
    for (int j2 = 0; j2 < 2; ++j2)
#pragma unroll
      for (int bb = 0; bb < 4; ++bb) {
        accA[j2][bb] += __shfl_xor(accA[j2][bb], off, 64);
        accB[j2][bb] += __shfl_xor(accB[j2][bb], off, 64);
      }
  }
  float* gsc = SM + 13824;
  if (kc == 0) {
#pragma unroll
    for (int j2 = 0; j2 < 2; ++j2)
#pragma unroll
      for (int bb = 0; bb < 4; ++bb) {
        gsc[(jlp * 2 + j2) * 32 + b4 * 4 + bb] = accA[j2][bb];
        gsc[256 + (jlp * 2 + j2) * 32 + b4 * 4 + bb] = accB[j2][bb];
      }
  }
  __syncthreads();
  if (tid < 64) {
    const int b = tid >> 1, dl = tid & 1, d = (wg << 1) | dl;
    if (doA) {
      const float gi = gsc[(0 + dl) * 32 + b] + Pp[b * 2048 + d];
      const float gf = gsc[(2 + dl) * 32 + b] + Pp[b * 2048 + 512 + d];
      const float gg = gsc[(4 + dl) * 32 + b] + Pp[b * 2048 + 1024 + d];
      const float go = gsc[(6 + dl) * 32 + b] + Pp[b * 2048 + 1536 + d];
      c0 = sigm(gf) * c0 + sigm(gi) * tanhf(gg);
      H0w[b * 512 + d] = sigm(go) * tanhf(c0);
    }
    if (doB) {
      const float gi = gsc[256 + (0 + dl) * 32 + b] + bih[2048 + d] + bhh[2048 + d];
      const float gf = gsc[256 + (2 + dl) * 32 + b] + bih[2048 + 512 + d] + bhh[2048 + 512 + d];
      const float gg = gsc[256 + (4 + dl) * 32 + b] + bih[2048 + 1024 + d] + bhh[2048 + 1024 + d];
      const float go = gsc[256 + (6 + dl) * 32 + b] + bih[2048 + 1536 + d] + bhh[2048 + 1536 + d];
      c1 = sigm(gf) * c1 + sigm(gi) * tanhf(gg);
      const float h = sigm(go) * tanhf(c1);
      H1w[b * 512 + d] = h;
      if (HlP) HlP[b * 512 + d] = h;
    }
  }
}

// ---- fc + attention + context for one batch row (WGs 0..31) ----
__device__ void phaseCDE(int b, int tid, const float* __restrict__ H1c,
                         const float* __restrict__ Wfc, const float* __restrict__ bfc,
                         const int* __restrict__ src, const float* __restrict__ Esrc,
                         float* __restrict__ oT, float* __restrict__ cX, float* __restrict__ SM)
{
  float* rb = SM + 14336;
  float* sc = SM + 13824;
  int* ib = (int*)(SM + 15360);
  float* red = SM + 15872;
  rb[tid] = H1c[b * 512 + tid];
  ib[tid] = src[b * 512 + tid];
  __syncthreads();
  const int w = tid >> 6, lane = tid & 63;
  for (int d = w; d < 512; d += 8) {
    const float* wr = Wfc + (size_t)d * 512;
    float p = 0.f;
#pragma unroll
    for (int i = 0; i < 8; ++i) p = fmaf(rb[lane * 8 + i], wr[lane * 8 + i], p);
    p = wredsum(p);
    if (lane == 0) { p += bfc[d]; rb[512 + d] = p; oT[b * 512 + d] = p; }
  }
  __syncthreads();
  for (int s = w; s < 512; s += 8) {
    const float* er = Esrc + (size_t)ib[s] * 512;
    float p = 0.f;
#pragma unroll
    for (int i = 0; i < 8; ++i) p = fmaf(rb[512 + lane * 8 + i], er[lane * 8 + i], p);
    p = wredsum(p);
    if (lane == 0) sc[s] = p * SCALE_INV;
  }
  __syncthreads();
  const float mx = blockMax(sc[tid], red, tid);
  const float e = expf(sc[tid] - mx);
  sc[tid] = e;
  const float sum = blockSum(e, red, tid);
  const float inv = 1.0f / sum;
  float acc = 0.f;
  const int d = tid;
#pragma unroll 4
  for (int s = 0; s < 512; ++s) acc = fmaf(sc[s], Esrc[(size_t)ib[s] * 512 + d], acc);
  cX[b * 512 + d] = acc * inv;
}

// ---- hid = relu([out|ctx] @ Wh2o^T + b) ----
__device__ void phaseF(int wg, int tid, const float* __restrict__ oT, const float* __restrict__ cX,
                       const float* __restrict__ Wh2o, const float* __restrict__ bh2o,
                       float* __restrict__ hD, float* __restrict__ SM)
{
  float* rb = SM + 14336;
  const int b = wg >> 3, d0 = (wg & 7) * 64;
  rb[tid] = oT[b * 512 + tid];
  rb[512 + tid] = cX[b * 512 + tid];
  __syncthreads();
  const int w = tid >> 6, lane = tid & 63;
  for (int dd = w; dd < 64; dd += 8) {
    const int d = d0 + dd;
    const float* wr = Wh2o + (size_t)d * 1024;
    float p = 0.f;
#pragma unroll
    for (int i = 0; i < 16; ++i) p = fmaf(rb[lane * 16 + i], wr[lane * 16 + i], p);
    p = wredsum(p);
    if (lane == 0) hD[b * 512 + d] = fmaxf(p + bh2o[d], 0.f);
  }
}

// ---- logits + per-slot argmax candidates, coalesced via pre-transposed E ----
__device__ void phaseG_ET(int wg, int tid, const float* __restrict__ hD, const float* __restrict__ ET,
                          const float* __restrict__ bout, float* __restrict__ candV,
                          int* __restrict__ candI, float* __restrict__ SM)
{
  if (wg >= 250) return;
  const int v0 = wg * 128;
  float* gv = SM + 13824;
  int* gi = (int*)(SM + 13824 + 128);
#pragma unroll 1
  for (int ph = 0; ph < 2; ++ph) {
    const int bbase = ph * 16;
    __syncthreads();
    for (int e = tid; e < 16 * 512; e += TPB) {   // hidT[k][b] (pad 18)
      const int b = e >> 9, k = e & 511;
      SM[k * 18 + b] = hD[(size_t)(bbase + b) * 512 + k];
    }
    __syncthreads();
    const int vp = tid >> 3, bh = tid & 7;
    const int v = v0 + vp * 2;
    float a00 = 0.f, a01 = 0.f, a10 = 0.f, a11 = 0.f;
    const float* ep = ET + v;
    const float* hp = SM + bh * 2;
#pragma unroll 4
    for (int k = 0; k < 512; ++k) {
      const float2 e2 = *(const float2*)(ep + (size_t)k * 32000);
      const float2 h2 = *(const float2*)(hp + (size_t)k * 18);
      a00 = fmaf(e2.x, h2.x, a00);
      a01 = fmaf(e2.x, h2.y, a01);
      a10 = fmaf(e2.y, h2.x, a10);
      a11 = fmaf(e2.y, h2.y, a11);
    }
    const float bo0 = bout[v], bo1 = bout[v + 1];
    a00 += bo0; a01 += bo0; a10 += bo1; a11 += bo1;
    float vA, vB; int iA, iB;
    if (a10 > a00) { vA = a10; iA = v + 1; } else { vA = a00; iA = v; }
    if (a11 > a01) { vB = a11; iB = v + 1; } else { vB = a01; iB = v; }
#pragma unroll
    for (int off = 8; off < 64; off <<= 1) {
      float ov = __shfl_xor(vA, off, 64); int oi = __shfl_xor(iA, off, 64);
      if (ov > vA || (ov == vA && oi < iA)) { vA = ov; iA = oi; }
      ov = __shfl_xor(vB, off, 64); oi = __shfl_xor(iB, off, 64);
      if (ov > vB || (ov == vB && oi < iB)) { vB = ov; iB = oi; }
    }
    if ((tid & 63) < 8) {
      const int w = tid >> 6;
      gv[(bh * 2 + 0) * 8 + w] = vA; gi[(bh * 2 + 0) * 8 + w] = iA;
      gv[(bh * 2 + 1) * 8 + w] = vB; gi[(bh * 2 + 1) * 8 + w] = iB;
    }
    __syncthreads();
    if (tid < 16) {
      float bv = -INFINITY; int bi = 0;
      for (int w2 = 0; w2 < 8; ++w2) {
        const float vv = gv[tid * 8 + w2]; const int ii = gi[tid * 8 + w2];
        if (vv > bv || (vv == bv && ii < bi)) { bv = vv; bi = ii; }
      }
      candV[(size_t)(bbase + tid) * 256 + wg] = bv;
      candI[(bbase + tid) * 256 + wg] = bi;
    }
  }
}

// ---- fallback logits (row-major E), wave-per-v ----
__device__ void phaseG_noET(int wg, int tid, const float* __restrict__ hD,
                            const float* __restrict__ Etrg, const float* __restrict__ bout,
                            float* __restrict__ candV, int* __restrict__ candI, float* __restrict__ SM)
{
  const int b = wg >> 3, vb = wg & 7;
  float* rb = SM + 14336;
  float* gv = SM + 13824;
  int* gi = (int*)(SM + 13824 + 64);
  rb[tid] = hD[(size_t)b * 512 + tid];
  __syncthreads();
  const int w = tid >> 6, lane = tid & 63;
  float bv = -INFINITY; int bi = 0;
  for (int v = vb * 4000 + w; v < (vb + 1) * 4000; v += 8) {
    const float* er = Etrg + (size_t)v * 512;
    float p = 0.f;
#pragma unroll
    for (int i = 0; i < 8; ++i) p = fmaf(rb[lane * 8 + i], er[lane * 8 + i], p);
    p = wredsum(p);
    p += bout[v];
    if (p > bv || (p == bv && v < bi)) { bv = p; bi = v; }
  }
  if (lane == 0) { gv[w] = bv; gi[w] = bi; }
  __syncthreads();
  if (tid == 0) {
    float fv = -INFINITY; int fi = 0;
    for (int w2 = 0; w2 < 8; ++w2)
      if (gv[w2] > fv || (gv[w2] == fv && gi[w2] < fi)) { fv = gv[w2]; fi = gi[w2]; }
    candV[(size_t)b * 256 + vb] = fv; candI[b * 256 + vb] = fi;
  }
}

// ---- token argmax finalize + next-position P = emb@Wih0^T + biases ----
__device__ void phaseHP(int wg, int tid, int t, bool useET,
                        const float* __restrict__ candV, const int* __restrict__ candI,
                        const float* __restrict__ Etrg, const float* __restrict__ Wih,
                        const float* __restrict__ bih, const float* __restrict__ bhh,
                        float* __restrict__ P, float* __restrict__ out, float* __restrict__ SM)
{
  int* tokL = (int*)(SM + 15360);
  const int nslot = useET ? 250 : 8;
  if (tid < 32) {
    const int b = tid;
    float bv = -INFINITY; int bi = 0;
    for (int s = 0; s < nslot; ++s) {
      const float vv = candV[(size_t)b * 256 + s]; const int ii = candI[b * 256 + s];
      if (vv > bv || (vv == bv && ii < bi)) { bv = vv; bi = ii; }
    }
    tokL[b] = bi;
    if (wg == 0) out[b * 32 + t] = (float)bi;   // tokens[:,1:][b][t]
  }
  __syncthreads();
  if (t < 31) {
    const int w = tid >> 6, lane = tid & 63;
    const int q = w >> 1, dl = w & 1;
    const int j = q * 512 + wg * 2 + dl;
    const float* wr = Wih + (size_t)j * 512;
    const float bsum = bih[j] + bhh[j];
    for (int b = 0; b < 32; ++b) {
      const float* er = Etrg + (size_t)tokL[b] * 512;
      float p = 0.f;
#pragma unroll
      for (int i = 0; i < 8; ++i) p = fmaf(er[lane * 8 + i], wr[lane * 8 + i], p);
      p = wredsum(p);
      if (lane == 0) P[((size_t)(t + 1) * 32 + b) * 2048 + j] = p + bsum;
    }
  }
}

// ---- outfc[p][b][:] = Hlast[p][b] @ Wfc^T + bfc ----
__device__ void phaseX(int wg, int tid, const float* __restrict__ Hl, const float* __restrict__ Wfc,
                       const float* __restrict__ bfc, float* __restrict__ oF)
{
  const int p = wg >> 3, bq = wg & 7;
  const int w = tid >> 6, lane = tid & 63;
  for (int u = w; u < 2048; u += 8) {
    const int bb = u >> 9, d = u & 511;
    const int b = bq * 4 + bb;
    const float* hr = Hl + ((size_t)p * 32 + b) * 512;
    const float* wr = Wfc + (size_t)d * 512;
    float acc = 0.f;
#pragma unroll
    for (int i = 0; i < 8; ++i) acc = fmaf(hr[lane * 8 + i], wr[lane * 8 + i], acc);
    acc = wredsum(acc);
    if (lane == 0) oF[((size_t)p * 32 + b) * 512 + d] = acc + bfc[d];
  }
}

// ---- final attn rows: softmax_s(outfc[p][b] . src_e[b][s] / sqrt(D)) ----
__device__ void phaseY(int wg, int tid, const float* __restrict__ oF, const int* __restrict__ src,
                       const float* __restrict__ Esrc, float* __restrict__ out, float* __restrict__ SM)
{
  float* rb = SM + 14336;
  float* sc = SM + 13824;
  int* ib = (int*)(SM + 15360);
  float* red = SM + 15872;
  for (int r = 0; r < 4; ++r) {
    const int id = wg * 4 + r;
    const int b = id >> 5, p = id & 31;
    __syncthreads();
    rb[tid] = oF[((size_t)p * 32 + b) * 512 + tid];
    ib[tid] = src[b * 512 + tid];
    __syncthreads();
    const int w = tid >> 6, lane = tid & 63;
    for (int s = w; s < 512; s += 8) {
      const float* er = Esrc + (size_t)ib[s] * 512;
      float acc = 0.f;
#pragma unroll
      for (int i = 0; i < 8; ++i) acc = fmaf(rb[lane * 8 + i], er[lane * 8 + i], acc);
      acc = wredsum(acc);
      if (lane == 0) sc[s] = acc * SCALE_INV;
    }
    __syncthreads();
    const float mx = blockMax(sc[tid], red, tid);
    const float e = expf(sc[tid] - mx);
    const float sum = blockSum(e, red, tid);
    out[1024 + ((size_t)b * 32 + p) * 512 + tid] = e / sum;
  }
}

extern "C" __global__ void __launch_bounds__(TPB)
s2s_mega(const int* __restrict__ src, const float* __restrict__ Esrc, const float* __restrict__ Etrg,
         const float* __restrict__ Wih, const float* __restrict__ Whh,
         const float* __restrict__ bih, const float* __restrict__ bhh,
         const float* __restrict__ Wfc, const float* __restrict__ bfc,
         const float* __restrict__ Wh2o, const float* __restrict__ bh2o,
         const float* __restrict__ bout, float* __restrict__ out,
         float* __restrict__ ws, const float* __restrict__ ET, float* __restrict__ ETw)
{
  __shared__ float SM[16256];
  unsigned* sb = (unsigned*)ws;
  float* H0 = ws + OFF_H0;
  float* H1 = ws + OFF_H1;
  float* P  = ws + OFF_P;
  float* Hl = ws + OFF_HL;
  float* oT = ws + OFF_OT;
  float* cX = ws + OFF_CX;
  float* hD = ws + OFF_HD;
  float* oF = ws + OFF_OF;
  float* cV = ws + OFF_CV;
  int*   cI = (int*)(ws + OFF_CI);

  const int wg = blockIdx.x, tid = threadIdx.x;
  unsigned lg = 0u;
  float c0 = 0.f, c1 = 0.f;

  // ---- setup: zero H state, P[0] (SOS token = 1), ET transpose, weight staging ----
  {
    const int gid = wg * TPB + tid;
    if (gid < BD) H0[gid] = 0.f;
    else if (gid < 2 * BD) H1[gid - BD] = 0.f;
  }
  {
    const int w = tid >> 6, lane = tid & 63;
    const int q = w >> 1, dl = w & 1;
    const int j = q * 512 + wg * 2 + dl;
    const float* er = Etrg + 512;               // row of token 1 ([SOS])
    const float* wr = Wih + (size_t)j * 512;
    float p = 0.f;
#pragma unroll
    for (int i = 0; i < 8; ++i) p = fmaf(er[lane * 8 + i], wr[lane * 8 + i], p);
    p = wredsum(p);
    p += bih[j] + bhh[j];
    if (lane < 32) P[(size_t)lane * 2048 + j] = p;
  }
  if (ETw) transposeET(wg, tid, Etrg, ETw, SM);
  stageW(wg, tid, Wih, Whh, SM);
  gbar(sb, lg);

  int cur0 = 0, cur1 = 0;
  for (int t = 0; t < 32; ++t) {
    if (t > 0 && ET != nullptr) stageW(wg, tid, Wih, Whh, SM);  // G overwrote Wl
    for (int k = 0; k <= t + 1; ++k) {
      const bool doA = (k <= t), doB = (k >= 1);
      float* HlP = (t == 31 && doB) ? (Hl + (size_t)(k - 1) * BD) : nullptr;
      const int kp = (k < 32) ? k : 31;
      phaseAB(wg, tid, doA, doB,
              H0 + (size_t)cur0 * BD, H0 + (size_t)(cur0 ^ 1) * BD,
              H1 + (size_t)cur1 * BD, H1 + (size_t)(cur1 ^ 1) * BD,
              HlP, P + (size_t)kp * Bb * 2048, bih, bhh, SM, c0, c1);
      gbar(sb, lg);
      if (doA) cur0 ^= 1;
      if (doB) cur1 ^= 1;
    }
    if (wg < 32) phaseCDE(wg, tid, H1 + (size_t)cur1 * BD, Wfc, bfc, src, Esrc, oT, cX, SM);
    gbar(sb, lg);
    phaseF(wg, tid, oT, cX, Wh2o, bh2o, hD, SM);
    gbar(sb, lg);
    if (ET != nullptr) phaseG_ET(wg, tid, hD, ET, bout, cV, cI, SM);
    else               phaseG_noET(wg, tid, hD, Etrg, bout, cV, cI, SM);
    gbar(sb, lg);
    phaseHP(wg, tid, t, ET != nullptr, cV, cI, Etrg, Wih, bih, bhh, P, out, SM);
    gbar(sb, lg);
  }
  phaseX(wg, tid, Hl, Wfc, bfc, oF);
  gbar(sb, lg);
  phaseY(wg, tid, oF, src, Esrc, out, SM);
}

extern "C" void kernel_launch(void* const* d_in, const int* in_sizes, int n_in,
                              void* d_out, int out_size, void* d_ws, size_t ws_size,
                              hipStream_t stream) {
  const int*   src  = (const int*)d_in[0];
  const float* Esrc = (const float*)d_in[1];
  const float* Etrg = (const float*)d_in[2];
  const float* Wih  = (const float*)d_in[3];
  const float* Whh  = (const float*)d_in[4];
  const float* bih  = (const float*)d_in[5];
  const float* bhh  = (const float*)d_in[6];
  const float* Wfc  = (const float*)d_in[7];
  const float* bfc  = (const float*)d_in[8];
  const float* Wh2o = (const float*)d_in[9];
  const float* bh2o = (const float*)d_in[10];
  const float* bout = (const float*)d_in[11];
  float* ws = (float*)d_ws;

  const size_t needET = (OFF_ET + (size_t)512 * 32000) * sizeof(float);
  const bool useET = (ws_size >= needET);
  float* etw = useET ? (ws + OFF_ET) : nullptr;

  hipMemsetAsync(d_ws, 0, 2048, stream);   // barrier counters/generation
  s2s_mega<<<dim3(NWG), dim3(TPB), 0, stream>>>(
      src, Esrc, Etrg, Wih, Whh, bih, bhh, Wfc, bfc, Wh2o, bh2o, bout,
      (float*)d_out, ws, etw, etw);
}

// Round 2
// 23143.401 us; speedup vs baseline: 4.6996x; 4.6996x over previous
//
#include <hip/hip_runtime.h>
#include <math.h>

#define NWG 256
#define TPB 512
#define AGT __HIP_MEMORY_SCOPE_AGENT

// ---- sizes ----
static constexpr int Bb = 32, Dd = 512, Tt = 32, Vv = 32000;
static constexpr int BD = Bb * Dd;                       // 16384
static constexpr float SCALE_INV = 0.04419417382415922f; // 1/sqrt(512)

// ---- ws layout (float offsets) ----
static constexpr size_t OFF_H0 = 512;                    // sync region = first 2KB
static constexpr size_t OFF_H1 = OFF_H0 + 2 * (size_t)BD;
static constexpr size_t OFF_P  = OFF_H1 + 2 * (size_t)BD;             // [32][32][2048]
static constexpr size_t OFF_HL = OFF_P + (size_t)Tt * Bb * 2048;      // [32][32][512]
static constexpr size_t OFF_HD = OFF_HL + (size_t)Tt * BD + 3 * (size_t)BD;
static constexpr size_t OFF_OF = OFF_HD + BD;                          // [32][32][512]
static constexpr size_t OFF_CV = OFF_OF + (size_t)Tt * BD;             // [32][256]
static constexpr size_t OFF_CI = OFF_CV + 32 * 256;
static constexpr size_t OFF_ET = OFF_CI + 32 * 256;                    // [512][32000]

__device__ __forceinline__ float sigm(float x) { return 1.0f / (1.0f + expf(-x)); }

// ---- IC-coherent (sc1) access helpers: relaxed agent-scope atomics.
// These lower to plain global_load/store with device-scope cache bits —
// they bypass the non-coherent per-XCD L2s and hit the shared Infinity
// Cache directly. NO buffer_inv / buffer_wbl2 is ever emitted.
__device__ __forceinline__ float ldcv(const float* p) {
  unsigned u = __hip_atomic_load((const unsigned*)p, __ATOMIC_RELAXED, AGT);
  return __builtin_bit_cast(float, u);
}
__device__ __forceinline__ void stcv(float* p, float v) {
  __hip_atomic_store((unsigned*)p, __builtin_bit_cast(unsigned, v), __ATOMIC_RELAXED, AGT);
}
__device__ __forceinline__ float2 ldcv2(const float* p) {
  unsigned long long u = __hip_atomic_load((const unsigned long long*)p, __ATOMIC_RELAXED, AGT);
  return __builtin_bit_cast(float2, u);
}
__device__ __forceinline__ int ldcvi(const int* p) {
  return (int)__hip_atomic_load((const unsigned*)p, __ATOMIC_RELAXED, AGT);
}
__device__ __forceinline__ void stcvi(int* p, int v) {
  __hip_atomic_store((unsigned*)p, (unsigned)v, __ATOMIC_RELAXED, AGT);
}

__device__ __forceinline__ float wredsum(float v) {
#pragma unroll
  for (int off = 32; off > 0; off >>= 1) v += __shfl_xor(v, off, 64);
  return v;
}

// ---- fence-free 2-level grid barrier (256 WGs = 8 groups of 32) ----
// Data visibility: every wave drains its own (sc1) stores with vmcnt(0)
// before s_barrier; arrivals/flag are relaxed agent atomics at the IC.
__device__ __forceinline__ void gbar(unsigned* sb, unsigned& lg) {
  const unsigned tgt = lg + 1u;
  asm volatile("s_waitcnt vmcnt(0)" ::: "memory");
  __syncthreads();
  if (threadIdx.x == 0) {
    const int g = (int)blockIdx.x >> 5;
    unsigned a = __hip_atomic_fetch_add(&sb[g * 32], 1u, __ATOMIC_RELAXED, AGT);
    bool done = false;
    if (a == 31u) {
      __hip_atomic_store(&sb[g * 32], 0u, __ATOMIC_RELAXED, AGT);
      unsigned r = __hip_atomic_fetch_add(&sb[264], 1u, __ATOMIC_RELAXED, AGT);
      if (r == 7u) {
        __hip_atomic_store(&sb[264], 0u, __ATOMIC_RELAXED, AGT);
        __hip_atomic_store(&sb[288], tgt, __ATOMIC_RELAXED, AGT);
        done = true;
      }
    }
    if (!done) {
      while (__hip_atomic_load(&sb[288], __ATOMIC_RELAXED, AGT) < tgt)
        __builtin_amdgcn_s_sleep(2);
    }
  }
  lg = tgt;
  __syncthreads();
}

__device__ __forceinline__ float blockMax(float v, float* red, int tid) {
#pragma unroll
  for (int off = 32; off > 0; off >>= 1) v = fmaxf(v, __shfl_xor(v, off, 64));
  if ((tid & 63) == 0) red[tid >> 6] = v;
  __syncthreads();
  float m = red[0];
#pragma unroll
  for (int i = 1; i < 8; ++i) m = fmaxf(m, red[i]);
  __syncthreads();
  return m;
}

__device__ __forceinline__ float blockSum(float v, float* red, int tid) {
  v = wredsum(v);
  if ((tid & 63) == 0) red[tid >> 6] = v;
  __syncthreads();
  float s = 0.f;
#pragma unroll
  for (int i = 0; i < 8; ++i) s += red[i];
  __syncthreads();
  return s;
}

// ---- stage this WG's 24 weight rows into LDS (slant-packed: chunk kc at kc*36) ----
__device__ void stageW(int wg, int tid, const float* __restrict__ Wih,
                       const float* __restrict__ Whh, float* __restrict__ SM) {
  for (int e = tid; e < 3 * 8 * 512; e += TPB) {
    const int k = e & 511, jl = (e >> 9) & 7, m = e >> 12;
    const int q = jl >> 1, dl = jl & 1;
    const int j = q * 512 + wg * 2 + dl;
    const float* srcp = (m == 0) ? (Whh + (size_t)j * 512)
                     : (m == 1) ? (Wih + (size_t)2048 * 512 + (size_t)j * 512)
                                : (Whh + (size_t)2048 * 512 + (size_t)j * 512);
    SM[(m * 8 + jl) * 576 + (k >> 5) * 36 + (k & 31)] = srcp[k];
  }
  __syncthreads();
}

// ---- WG-private transpose: WG wg owns ET column panel [wg*128, wg*128+128).
// Writer == reader for every ET line -> normal cached access is safe.
__device__ void transposeET(int wg, int tid, const float* __restrict__ Etrg,
                            float* __restrict__ ETw, float* __restrict__ SM) {
  if (wg < 250) {
    for (int tile = 0; tile < 8; ++tile) {
      const int tv = tile >> 2, tk = tile & 3;
      __syncthreads();
      for (int e = tid; e < 64 * 128; e += TPB) {
        const int vl = e >> 7, kl = e & 127;
        SM[vl * 129 + kl] = Etrg[(size_t)(wg * 128 + tv * 64 + vl) * 512 + tk * 128 + kl];
      }
      __syncthreads();
      for (int e = tid; e < 64 * 128; e += TPB) {
        const int kl = e >> 6, vl = e & 63;
        ETw[(size_t)(tk * 128 + kl) * 32000 + wg * 128 + tv * 64 + vl] = SM[vl * 129 + kl];
      }
    }
    __syncthreads();
  }
}

// ---- merged LSTM phase: A = L0(pos p), B = L1(pos p-1).
// Mapping: tid = b*16 + kc  (b in [0,32), kc in [0,16) chunk of 32 k).
// Each H element loaded exactly once per WG (sc1/IC-coherent).
__device__ __forceinline__ void phaseAB(
    int wg, int tid, bool doA, bool doB,
    const float* __restrict__ H0r, float* __restrict__ H0w,
    const float* __restrict__ H1r, float* __restrict__ H1w,
    float* __restrict__ HlP, const float* __restrict__ Pp,
    const float* __restrict__ bs1,
    const float* __restrict__ SM, float& c0, float& c1)
{
  const int b = tid >> 4, kc = tid & 15;
  float h[32], accA[8], accB[8];
#pragma unroll
  for (int r = 0; r < 8; ++r) { accA[r] = 0.f; accB[r] = 0.f; }
  const float* hp0 = H0r + b * 512 + kc * 32;
#pragma unroll
  for (int i = 0; i < 16; ++i) {
    float2 v = ldcv2(hp0 + 2 * i);
    h[2 * i] = v.x; h[2 * i + 1] = v.y;
  }
  if (doA) {
#pragma unroll
    for (int r = 0; r < 8; ++r) {
      const float4* wr = (const float4*)(SM + r * 576 + kc * 36);
#pragma unroll
      for (int iq = 0; iq < 8; ++iq) {
        float4 w = wr[iq];
        accA[r] = fmaf(w.x, h[iq * 4 + 0], accA[r]);
        accA[r] = fmaf(w.y, h[iq * 4 + 1], accA[r]);
        accA[r] = fmaf(w.z, h[iq * 4 + 2], accA[r]);
        accA[r] = fmaf(w.w, h[iq * 4 + 3], accA[r]);
      }
    }
  }
  if (doB) {
#pragma unroll
    for (int r = 0; r < 8; ++r) {       // Wih1 . H0
      const float4* wr = (const float4*)(SM + (8 + r) * 576 + kc * 36);
#pragma unroll
      for (int iq = 0; iq < 8; ++iq) {
        float4 w = wr[iq];
        accB[r] = fmaf(w.x, h[iq * 4 + 0], accB[r]);
        accB[r] = fmaf(w.y, h[iq * 4 + 1], accB[r]);
        accB[r] = fmaf(w.z, h[iq * 4 + 2], accB[r]);
        accB[r] = fmaf(w.w, h[iq * 4 + 3], accB[r]);
      }
    }
    const float* hp1 = H1r + b * 512 + kc * 32;
#pragma unroll
    for (int i = 0; i < 16; ++i) {
      float2 v = ldcv2(hp1 + 2 * i);
      h[2 * i] = v.x; h[2 * i + 1] = v.y;
    }
#pragma unroll
    for (int r = 0; r < 8; ++r) {       // Whh1 . H1
      const float4* wr = (const float4*)(SM + (16 + r) * 576 + kc * 36);
#pragma unroll
      for (int iq = 0; iq < 8; ++iq) {
        float4 w = wr[iq];
        accB[r] = fmaf(w.x, h[iq * 4 + 0], accB[r]);
        accB[r] = fmaf(w.y, h[iq * 4 + 1], accB[r]);
        accB[r] = fmaf(w.z, h[iq * 4 + 2], accB[r]);
        accB[r] = fmaf(w.w, h[iq * 4 + 3], accB[r]);
      }
    }
  }
#pragma unroll
  for (int off = 1; off < 16; off <<= 1) {   // reduce over the 16 kc lanes
    if (doA) {
#pragma unroll
      for (int r = 0; r < 8; ++r) accA[r] += __shfl_xor(accA[r], off, 64);
    }
    if (doB) {
#pragma unroll
      for (int r = 0; r < 8; ++r) accB[r] += __shfl_xor(accB[r], off, 64);
    }
  }
  if (kc < 2) {                        // lanes kc=0,1 own columns d = wg*2+kc
    const int d = (wg << 1) | kc;
    if (doA) {
      const float* pb = Pp + b * 2048 + d;
      const float gi = accA[0 + kc] + pb[0];
      const float gf = accA[2 + kc] + pb[512];
      const float gg = accA[4 + kc] + pb[1024];
      const float go = accA[6 + kc] + pb[1536];
      c0 = sigm(gf) * c0 + sigm(gi) * tanhf(gg);
      stcv(H0w + b * 512 + d, sigm(go) * tanhf(c0));
    }
    if (doB) {
      const float gi = accB[0 + kc] + bs1[0];
      const float gf = accB[2 + kc] + bs1[1];
      const float gg = accB[4 + kc] + bs1[2];
      const float go = accB[6 + kc] + bs1[3];
      c1 = sigm(gf) * c1 + sigm(gi) * tanhf(gg);
      const float hn = sigm(go) * tanhf(c1);
      stcv(H1w + b * 512 + d, hn);
      if (HlP) stcv(HlP + b * 512 + d, hn);
    }
  }
}

// ---- fused fc + attention + context + h2o for one batch row (WGs 0..31) ----
__device__ void phaseCDEF(int b, int tid, const float* __restrict__ H1c,
                          const float* __restrict__ Wfc, const float* __restrict__ bfc,
                          const int* __restrict__ src, const float* __restrict__ Esrc,
                          const float* __restrict__ Wh2o, const float* __restrict__ bh2o,
                          float* __restrict__ hD, float* __restrict__ SM)
{
  float* sc = SM + 13824;
  float* rb = SM + 14336;
  int* ib = (int*)(SM + 15360);
  float* red = SM + 15872;
  rb[tid] = ldcv(H1c + b * 512 + tid);
  ib[tid] = src[b * 512 + tid];
  __syncthreads();
  const int w = tid >> 6, lane = tid & 63;
  for (int d = w; d < 512; d += 8) {            // fc_out
    const float* wr = Wfc + (size_t)d * 512;
    float p = 0.f;
#pragma unroll
    for (int i = 0; i < 8; ++i) p = fmaf(rb[lane * 8 + i], wr[lane * 8 + i], p);
    p = wredsum(p);
    if (lane == 0) rb[512 + d] = p + bfc[d];
  }
  __syncthreads();
  for (int s = w; s < 512; s += 8) {            // scores
    const float* er = Esrc + (size_t)ib[s] * 512;
    float p = 0.f;
#pragma unroll
    for (int i = 0; i < 8; ++i) p = fmaf(rb[512 + lane * 8 + i], er[lane * 8 + i], p);
    p = wredsum(p);
    if (lane == 0) sc[s] = p * SCALE_INV;
  }
  __syncthreads();
  const float mx = blockMax(sc[tid], red, tid);
  const float e = expf(sc[tid] - mx);
  sc[tid] = e;
  const float sum = blockSum(e, red, tid);
  const float inv = 1.0f / sum;
  float acc = 0.f;
#pragma unroll 4
  for (int s = 0; s < 512; ++s) acc = fmaf(sc[s], Esrc[(size_t)ib[s] * 512 + tid], acc);
  rb[tid] = acc * inv;                          // ctx into rb[0:512]
  __syncthreads();
  for (int d = w; d < 512; d += 8) {            // h2o + relu
    const float* wr = Wh2o + (size_t)d * 1024;
    float p = 0.f;
#pragma unroll
    for (int i = 0; i < 8; ++i) p = fmaf(rb[512 + lane * 8 + i], wr[lane * 8 + i], p);
#pragma unroll
    for (int i = 0; i < 8; ++i) p = fmaf(rb[lane * 8 + i], wr[512 + lane * 8 + i], p);
    p = wredsum(p);
    if (lane == 0) stcv(hD + (size_t)b * 512 + d, fmaxf(p + bh2o[d], 0.f));
  }
}

// ---- logits + per-slot argmax candidates, coalesced via WG-private ET panel ----
__device__ void phaseG_ET(int wg, int tid, const float* __restrict__ hD, const float* __restrict__ ET,
                          const float* __restrict__ bout, float* __restrict__ candV,
                          int* __restrict__ candI, float* __restrict__ SM)
{
  if (wg >= 250) return;
  const int v0 = wg * 128;
  float* gv = SM + 13824;
  int* gi = (int*)(SM + 13824 + 128);
#pragma unroll 1
  for (int ph = 0; ph < 2; ++ph) {
    const int bbase = ph * 16;
    __syncthreads();
    for (int e = tid; e < 16 * 512; e += TPB) {   // hidT[k][b] (pad 18)
      const int b = e >> 9, k = e & 511;
      SM[k * 18 + b] = ldcv(hD + (size_t)(bbase + b) * 512 + k);
    }
    __syncthreads();
    const int vp = tid >> 3, bh = tid & 7;
    const int v = v0 + vp * 2;
    float a00 = 0.f, a01 = 0.f, a10 = 0.f, a11 = 0.f;
    const float* ep = ET + v;
    const float* hp = SM + bh * 2;
#pragma unroll 4
    for (int k = 0; k < 512; ++k) {
      const float2 e2 = *(const float2*)(ep + (size_t)k * 32000);
      const float2 h2 = *(const float2*)(hp + (size_t)k * 18);
      a00 = fmaf(e2.x, h2.x, a00);
      a01 = fmaf(e2.x, h2.y, a01);
      a10 = fmaf(e2.y, h2.x, a10);
      a11 = fmaf(e2.y, h2.y, a11);
    }
    const float bo0 = bout[v], bo1 = bout[v + 1];
    a00 += bo0; a01 += bo0; a10 += bo1; a11 += bo1;
    float vA, vB; int iA, iB;
    if (a10 > a00) { vA = a10; iA = v + 1; } else { vA = a00; iA = v; }
    if (a11 > a01) { vB = a11; iB = v + 1; } else { vB = a01; iB = v; }
#pragma unroll
    for (int off = 8; off < 64; off <<= 1) {
      float ov = __shfl_xor(vA, off, 64); int oi = __shfl_xor(iA, off, 64);
      if (ov > vA || (ov == vA && oi < iA)) { vA = ov; iA = oi; }
      ov = __shfl_xor(vB, off, 64); oi = __shfl_xor(iB, off, 64);
      if (ov > vB || (ov == vB && oi < iB)) { vB = ov; iB = oi; }
    }
    if ((tid & 63) < 8) {
      const int w = tid >> 6;
      gv[(bh * 2 + 0) * 8 + w] = vA; gi[(bh * 2 + 0) * 8 + w] = iA;
      gv[(bh * 2 + 1) * 8 + w] = vB; gi[(bh * 2 + 1) * 8 + w] = iB;
    }
    __syncthreads();
    if (tid < 16) {
      float bv = -INFINITY; int bi = 0;
      for (int w2 = 0; w2 < 8; ++w2) {
        const float vv = gv[tid * 8 + w2]; const int ii = gi[tid * 8 + w2];
        if (vv > bv || (vv == bv && ii < bi)) { bv = vv; bi = ii; }
      }
      stcv(candV + (size_t)(bbase + tid) * 256 + wg, bv);
      stcvi(candI + (bbase + tid) * 256 + wg, bi);
    }
  }
}

// ---- fallback logits (row-major E), wave-per-v ----
__device__ void phaseG_noET(int wg, int tid, const float* __restrict__ hD,
                            const float* __restrict__ Etrg, const float* __restrict__ bout,
                            float* __restrict__ candV, int* __restrict__ candI, float* __restrict__ SM)
{
  const int b = wg >> 3, vb = wg & 7;
  float* rb = SM + 14336;
  float* gv = SM + 13824;
  int* gi = (int*)(SM + 13824 + 64);
  rb[tid] = ldcv(hD + (size_t)b * 512 + tid);
  __syncthreads();
  const int w = tid >> 6, lane = tid & 63;
  float bv = -INFINITY; int bi = 0;
  for (int v = vb * 4000 + w; v < (vb + 1) * 4000; v += 8) {
    const float* er = Etrg + (size_t)v * 512;
    float p = 0.f;
#pragma unroll
    for (int i = 0; i < 8; ++i) p = fmaf(rb[lane * 8 + i], er[lane * 8 + i], p);
    p = wredsum(p);
    p += bout[v];
    if (p > bv || (p == bv && v < bi)) { bv = p; bi = v; }
  }
  if (lane == 0) { gv[w] = bv; gi[w] = bi; }
  __syncthreads();
  if (tid == 0) {
    float fv = -INFINITY; int fi = 0;
    for (int w2 = 0; w2 < 8; ++w2)
      if (gv[w2] > fv || (gv[w2] == fv && gi[w2] < fi)) { fv = gv[w2]; fi = gi[w2]; }
    stcv(candV + (size_t)b * 256 + vb, fv);
    stcvi(candI + b * 256 + vb, fi);
  }
}

// ---- token argmax finalize (16-lane parallel scan) + P[t+1] projection ----
__device__ void phaseHP(int wg, int tid, int t, bool useET,
                        const float* __restrict__ candV, const int* __restrict__ candI,
                        const float* __restrict__ Etrg, const float* __restrict__ Wih,
                        const float* __restrict__ bih, const float* __restrict__ bhh,
                        float* __restrict__ P, float* __restrict__ out, float* __restrict__ SM)
{
  int* tokL = (int*)(SM + 15360);
  const int nslot = useET ? 250 : 8;
  {
    const int b = tid >> 4, sl = tid & 15;
    float bv = -INFINITY; int bi = 0x7fffffff;
    for (int s = sl; s < nslot; s += 16) {
      const float vv = ldcv(candV + (size_t)b * 256 + s);
      const int ii = ldcvi(candI + b * 256 + s);
      if (vv > bv || (vv == bv && ii < bi)) { bv = vv; bi = ii; }
    }
#pragma unroll
    for (int off = 1; off < 16; off <<= 1) {
      const float ov = __shfl_xor(bv, off, 64); const int oi = __shfl_xor(bi, off, 64);
      if (ov > bv || (ov == bv && oi < bi)) { bv = ov; bi = oi; }
    }
    if (sl == 0) {
      tokL[b] = bi;
      if (wg == 0) out[b * 32 + t] = (float)bi;   // tokens[:,1:][b][t]
    }
  }
  __syncthreads();
  if (t < 31) {
    const int w = tid >> 6, lane = tid & 63;
    const int q = w >> 1, dl = w & 1;
    const int j = q * 512 + wg * 2 + dl;
    const float* wr = Wih + (size_t)j * 512;
    const float bsum = bih[j] + bhh[j];
    for (int b = 0; b < 32; ++b) {
      const float* er = Etrg + (size_t)tokL[b] * 512;
      float p = 0.f;
#pragma unroll
      for (int i = 0; i < 8; ++i) p = fmaf(er[lane * 8 + i], wr[lane * 8 + i], p);
      p = wredsum(p);
      if (lane == 0) P[((size_t)(t + 1) * 32 + b) * 2048 + j] = p + bsum;
    }
  }
}

// ---- outfc[p][b][:] = Hlast[p][b] @ Wfc^T + bfc ----
__device__ void phaseX(int wg, int tid, const float* __restrict__ Hl, const float* __restrict__ Wfc,
                       const float* __restrict__ bfc, float* __restrict__ oF)
{
  const int p = wg >> 3, bq = wg & 7;
  const int w = tid >> 6, lane = tid & 63;
  for (int u = w; u < 2048; u += 8) {
    const int bb = u >> 9, d = u & 511;
    const int b = bq * 4 + bb;
    const float* hr = Hl + ((size_t)p * 32 + b) * 512;
    const float* wr = Wfc + (size_t)d * 512;
    float acc = 0.f;
#pragma unroll
    for (int ii = 0; ii < 4; ++ii) {
      const float2 hv = ldcv2(hr + lane * 8 + 2 * ii);
      acc = fmaf(hv.x, wr[lane * 8 + 2 * ii], acc);
      acc = fmaf(hv.y, wr[lane * 8 + 2 * ii + 1], acc);
    }
    acc = wredsum(acc);
    if (lane == 0) stcv(oF + ((size_t)p * 32 + b) * 512 + d, acc + bfc[d]);
  }
}

// ---- final attn rows: softmax_s(outfc[p][b] . src_e[b][s] / sqrt(D)) ----
__device__ void phaseY(int wg, int tid, const float* __restrict__ oF, const int* __restrict__ src,
                       const float* __restrict__ Esrc, float* __restrict__ out, float* __restrict__ SM)
{
  float* rb = SM + 14336;
  float* sc = SM + 13824;
  int* ib = (int*)(SM + 15360);
  float* red = SM + 15872;
  for (int r = 0; r < 4; ++r) {
    const int id = wg * 4 + r;
    const int b = id >> 5, p = id & 31;
    __syncthreads();
    rb[tid] = ldcv(oF + ((size_t)p * 32 + b) * 512 + tid);
    ib[tid] = src[b * 512 + tid];
    __syncthreads();
    const int w = tid >> 6, lane = tid & 63;
    for (int s = w; s < 512; s += 8) {
      const float* er = Esrc + (size_t)ib[s] * 512;
      float acc = 0.f;
#pragma unroll
      for (int i = 0; i < 8; ++i) acc = fmaf(rb[lane * 8 + i], er[lane * 8 + i], acc);
      acc = wredsum(acc);
      if (lane == 0) sc[s] = acc * SCALE_INV;
    }
    __syncthreads();
    const float mx = blockMax(sc[tid], red, tid);
    const float e = expf(sc[tid] - mx);
    const float sum = blockSum(e, red, tid);
    out[1024 + ((size_t)b * 32 + p) * 512 + tid] = e / sum;
  }
}

extern "C" __global__ void __launch_bounds__(TPB)
s2s_mega(const int* __restrict__ src, const float* __restrict__ Esrc, const float* __restrict__ Etrg,
         const float* __restrict__ Wih, const float* __restrict__ Whh,
         const float* __restrict__ bih, const float* __restrict__ bhh,
         const float* __restrict__ Wfc, const float* __restrict__ bfc,
         const float* __restrict__ Wh2o, const float* __restrict__ bh2o,
         const float* __restrict__ bout, float* __restrict__ out,
         float* __restrict__ ws, const float* __restrict__ ET, float* __restrict__ ETw)
{
  __shared__ float SM[16256];
  unsigned* sb = (unsigned*)ws;
  float* H0 = ws + OFF_H0;
  float* H1 = ws + OFF_H1;
  float* P  = ws + OFF_P;
  float* Hl = ws + OFF_HL;
  float* hD = ws + OFF_HD;
  float* oF = ws + OFF_OF;
  float* cV = ws + OFF_CV;
  int*   cI = (int*)(ws + OFF_CI);

  const int wg = blockIdx.x, tid = threadIdx.x;
  unsigned lg = 0u;
  float c0 = 0.f, c1 = 0.f;

  // layer-1 biases for this thread's owned column (lanes kc<2 only use these)
  float bs1[4] = {0.f, 0.f, 0.f, 0.f};
  {
    const int kc = tid & 15;
    if (kc < 2) {
      const int d = (wg << 1) | kc;
#pragma unroll
      for (int q = 0; q < 4; ++q)
        bs1[q] = bih[2048 + q * 512 + d] + bhh[2048 + q * 512 + d];
    }
  }

  // ---- setup: zero carried H state (buffer 0 of each ping-pong pair) ----
  {
    const int gid = wg * TPB + tid;
    if (gid < BD) stcv(H0 + gid, 0.f);
    else if (gid < 2 * BD) stcv(H1 + gid - BD, 0.f);
  }
  // ---- P[0] = emb([SOS]) @ Wih0^T + biases (same for all b) ----
  {
    const int w = tid >> 6, lane = tid & 63;
    const int q = w >> 1, dl = w & 1;
    const int j = q * 512 + wg * 2 + dl;
    const float* er = Etrg + 512;               // row of token 1 ([SOS])
    const float* wr = Wih + (size_t)j * 512;
    float p = 0.f;
#pragma unroll
    for (int i = 0; i < 8; ++i) p = fmaf(er[lane * 8 + i], wr[lane * 8 + i], p);
    p = wredsum(p);
    p += bih[j] + bhh[j];
    if (lane < 32) P[(size_t)lane * 2048 + j] = p;
  }
  if (ETw) transposeET(wg, tid, Etrg, ETw, SM);
  stageW(wg, tid, Wih, Whh, SM);
  gbar(sb, lg);

  int cur0 = 0, cur1 = 0;
  for (int t = 0; t < 32; ++t) {
    if (t > 0) stageW(wg, tid, Wih, Whh, SM);   // phaseG clobbered the weights
    for (int k = 0; k <= t + 1; ++k) {
      const bool doA = (k <= t), doB = (k >= 1);
      float* HlP = (t == 31 && doB) ? (Hl + (size_t)(k - 1) * BD) : nullptr;
      const int kp = (k < 32) ? k : 31;
      phaseAB(wg, tid, doA, doB,
              H0 + (size_t)cur0 * BD, H0 + (size_t)(cur0 ^ 1) * BD,
              H1 + (size_t)cur1 * BD, H1 + (size_t)(cur1 ^ 1) * BD,
              HlP, P + (size_t)kp * Bb * 2048, bs1, SM, c0, c1);
      gbar(sb, lg);
      if (doA) cur0 ^= 1;
      if (doB) cur1 ^= 1;
    }
    if (wg < 32) phaseCDEF(wg, tid, H1 + (size_t)cur1 * BD, Wfc, bfc, src, Esrc, Wh2o, bh2o, hD, SM);
    gbar(sb, lg);
    if (ET != nullptr) phaseG_ET(wg, tid, hD, ET, bout, cV, cI, SM);
    else               phaseG_noET(wg, tid, hD, Etrg, bout, cV, cI, SM);
    gbar(sb, lg);
    phaseHP(wg, tid, t, ET != nullptr, cV, cI, Etrg, Wih, bih, bhh, P, out, SM);
    gbar(sb, lg);
  }
  phaseX(wg, tid, Hl, Wfc, bfc, oF);
  gbar(sb, lg);
  phaseY(wg, tid, oF, src, Esrc, out, SM);
}

extern "C" void kernel_launch(void* const* d_in, const int* in_sizes, int n_in,
                              void* d_out, int out_size, void* d_ws, size_t ws_size,
                              hipStream_t stream) {
  const int*   src  = (const int*)d_in[0];
  const float* Esrc = (const float*)d_in[1];
  const float* Etrg = (const float*)d_in[2];
  const float* Wih  = (const float*)d_in[3];
  const float* Whh  = (const float*)d_in[4];
  const float* bih  = (const float*)d_in[5];
  const float* bhh  = (const float*)d_in[6];
  const float* Wfc  = (const float*)d_in[7];
  const float* bfc  = (const float*)d_in[8];
  const float* Wh2o = (const float*)d_in[9];
  const float* bh2o = (const float*)d_in[10];
  const float* bout = (const float*)d_in[11];
  float* ws = (float*)d_ws;

  const size_t needET = (OFF_ET + (size_t)512 * 32000) * sizeof(float);
  const bool useET = (ws_size >= needET);
  float* etw = useET ? (ws + OFF_ET) : nullptr;

  hipMemsetAsync(d_ws, 0, 2048, stream);   // reset barrier counters + generation flag
  s2s_mega<<<dim3(NWG), dim3(TPB), 0, stream>>>(
      src, Esrc, Etrg, Wih, Whh, bih, bhh, Wfc, bfc, Wh2o, bh2o, bout,
      (float*)d_out, ws, etw, etw);
}